// Round 13
// baseline (20178.891 us; speedup 1.0000x reference)
//
#include <hip/hip_runtime.h>

typedef unsigned short ushort_t;
typedef short sh8 __attribute__((ext_vector_type(8)));     // 8 bf16 (4 VGPR)
typedef float f32x4 __attribute__((ext_vector_type(4)));   // 4 fp32 acc

#define MFMA16(a,b,c) __builtin_amdgcn_mfma_f32_16x16x32_bf16((a),(b),(c),0,0,0)

#define SEQL   512
#define BATCH  64
#define HDIM   1024
#define G3     3072
#define AROWS  (SEQL*BATCH)          // 32768
#define YSZ    (SEQL*BATCH*HDIM)     // 33554432
#define BH     (BATCH*HDIM)          // 65536
#define NWG    64

__device__ __forceinline__ ushort_t f2bf(float x) {
  unsigned u = __float_as_uint(x);
  u += 0x7FFFu + ((u >> 16) & 1u);    // RNE
  return (ushort_t)(u >> 16);
}
__device__ __forceinline__ float bf2f(ushort_t h) {
  return __uint_as_float(((unsigned)h) << 16);
}

// ---------------- conversion / init ----------------
__global__ void cvt_kernel(const float* __restrict__ wih, const float* __restrict__ whh,
                           const float* __restrict__ h0,
                           ushort_t* __restrict__ WihH, ushort_t* __restrict__ WihL,
                           ushort_t* __restrict__ WhhH, ushort_t* __restrict__ WhhL,
                           unsigned* __restrict__ hU) {
  const int NW = G3 * HDIM;
  int i0 = blockIdx.x * blockDim.x + threadIdx.x;
  int stride = gridDim.x * blockDim.x;
  for (int i = i0; i < NW; i += stride) {
    float x = wih[i]; ushort_t h = f2bf(x);
    WihH[i] = h; WihL[i] = f2bf(x - bf2f(h));
    float y = whh[i]; ushort_t g = f2bf(y);
    WhhH[i] = g; WhhL[i] = f2bf(y - bf2f(g));
  }
  for (int i = i0; i < BH; i += stride) {
    hU[i] = (unsigned)f2bf(h0[i]);
  }
}

// ---------------- phase 1: gx = input @ W_ih^T + b_ih (3-term bf16) ----------------
__global__ __launch_bounds__(256) void gemm_gx(
    const float* __restrict__ A,            // [32768][1024] fp32
    const ushort_t* __restrict__ BHp, const ushort_t* __restrict__ BLp, // [3072][1024]
    const float* __restrict__ bias,         // [3072]
    float* __restrict__ gx)                 // [32768][3072]
{
  int bid = blockIdx.x;
  int mt = bid / 24, nt = bid % 24;
  int w = threadIdx.x >> 6, l = threadIdx.x & 63;
  int lr = l & 15, lk = (l >> 4) * 8;

  f32x4 acc[2][8];
  #pragma unroll
  for (int mi = 0; mi < 2; ++mi)
    #pragma unroll
    for (int ni = 0; ni < 8; ++ni) acc[mi][ni] = (f32x4){0.f, 0.f, 0.f, 0.f};

  int arow0 = mt * 128 + w * 32 + lr;
  int brow0 = nt * 128 + lr;

  for (int k0 = 0; k0 < HDIM; k0 += 32) {
    int ka = k0 + lk;
    sh8 aH[2], aL[2];
    #pragma unroll
    for (int mi = 0; mi < 2; ++mi) {
      const float* ap = A + (size_t)(arow0 + mi * 16) * HDIM + ka;
      float4 x0 = *(const float4*)ap;
      float4 x1 = *(const float4*)(ap + 4);
      float xs[8] = {x0.x, x0.y, x0.z, x0.w, x1.x, x1.y, x1.z, x1.w};
      #pragma unroll
      for (int j = 0; j < 8; ++j) {
        ushort_t h = f2bf(xs[j]);
        aH[mi][j] = (short)h;
        aL[mi][j] = (short)f2bf(xs[j] - bf2f(h));
      }
    }
    #pragma unroll
    for (int ni = 0; ni < 8; ++ni) {
      const ushort_t* bh = BHp + (size_t)(brow0 + ni * 16) * HDIM + ka;
      const ushort_t* bl = BLp + (size_t)(brow0 + ni * 16) * HDIM + ka;
      sh8 bHf = *(const sh8*)bh;
      sh8 bLf = *(const sh8*)bl;
      #pragma unroll
      for (int mi = 0; mi < 2; ++mi) {
        acc[mi][ni] = MFMA16(aH[mi], bHf, acc[mi][ni]);
        acc[mi][ni] = MFMA16(aH[mi], bLf, acc[mi][ni]);
        acc[mi][ni] = MFMA16(aL[mi], bHf, acc[mi][ni]);
      }
    }
  }
  int rb = (l >> 4) * 4;
  #pragma unroll
  for (int mi = 0; mi < 2; ++mi)
    #pragma unroll
    for (int ni = 0; ni < 8; ++ni) {
      int col = nt * 128 + ni * 16 + lr;
      float b = bias[col];
      #pragma unroll
      for (int j = 0; j < 4; ++j) {
        int row = mt * 128 + w * 32 + mi * 16 + rb + j;
        __builtin_nontemporal_store(acc[mi][ni][j] + b, &gx[(size_t)row * G3 + col]);
      }
    }
}

// ---------------- fence-free device barrier ----------------
// No release/acquire => no buffer_wbl2 / buffer_inv on the hot path.
// Correctness: each wave's __syncthreads entry drains vmcnt(0), so all agent-scope
// data stores are acked at L3 before the slot store issues. Data loads are
// agent-scope atomics (bypass L1/L2) so no invalidate is needed.
// Slots are DENSE (64 uints = 4 cachelines) so the 64-lane poll gather is 4 lines.
__device__ __forceinline__ void gbar_nf(unsigned* slots, int g, int tid, unsigned e) {
  __syncthreads();
  if (tid < 64) {
    if (tid == 0)
      __hip_atomic_store(slots + g, e, __ATOMIC_RELAXED, __HIP_MEMORY_SCOPE_AGENT);
    while (__hip_atomic_load(slots + tid, __ATOMIC_RELAXED, __HIP_MEMORY_SCOPE_AGENT) < e)
      __builtin_amdgcn_s_sleep(1);
  }
  __syncthreads();
}

// burst-load 32 chunks (8 bf16 each) from a uint-per-bf16 agent-coherent buffer,
// repacking into sh8 fragments
#define LOADU(BUF_, base_) \
  _Pragma("unroll") for (int i = 0; i < 32; ++i) { \
    unsigned long long* p = (unsigned long long*)((base_) + i * 32); \
    unsigned long long q0 = __hip_atomic_load(p + 0, __ATOMIC_RELAXED, __HIP_MEMORY_SCOPE_AGENT); \
    unsigned long long q1 = __hip_atomic_load(p + 1, __ATOMIC_RELAXED, __HIP_MEMORY_SCOPE_AGENT); \
    unsigned long long q2 = __hip_atomic_load(p + 2, __ATOMIC_RELAXED, __HIP_MEMORY_SCOPE_AGENT); \
    unsigned long long q3 = __hip_atomic_load(p + 3, __ATOMIC_RELAXED, __HIP_MEMORY_SCOPE_AGENT); \
    union { unsigned u[4]; sh8 s; } f_; \
    f_.u[0] = (unsigned)q0 | ((unsigned)(q0 >> 32) << 16); \
    f_.u[1] = (unsigned)q1 | ((unsigned)(q1 >> 32) << 16); \
    f_.u[2] = (unsigned)q2 | ((unsigned)(q2 >> 32) << 16); \
    f_.u[3] = (unsigned)q3 | ((unsigned)(q3 >> 32) << 16); \
    BUF_[i] = f_.s; }

// ---------------- phase 2: persistent recurrence ----------------
// 64 WGs x 256 threads. WG g owns hidden cols [16g,16g+16). Wave w owns rows [16w,16w+16).
// W_hh slices in LDS (128KB): rH@0, zH@32K, nH@64K, nL@96K, XOR-swizzled.
// Exchange (hU, rhU) via relaxed agent-scope atomics (L2-bypassing, L3-coherent).
__global__ __launch_bounds__(256, 1) void gru_rec(
    const float* __restrict__ gx,                 // [512][64][3072]
    const ushort_t* __restrict__ WhhH, const ushort_t* __restrict__ WhhL, // [3072][1024]
    const float* __restrict__ bias_hh,            // [3072]
    const float* __restrict__ h0f,                // [64][1024] fp32
    unsigned* hU,                                 // [2][64][1024] uint(bf16)
    unsigned* rhU,                                // [64][1024] uint(bf16)
    float* __restrict__ Y, float* __restrict__ Yh,
    unsigned* slots)
{
  extern __shared__ char lds[];
  const int g = blockIdx.x;
  const int tid = threadIdx.x;
  const int w = tid >> 6, l = tid & 63;
  const int lr = l & 15, lk = (l >> 4) * 8, rb = (l >> 4) * 4;
  const int c0 = g * 16, m0 = w * 16;
  const int c = c0 + lr;

  // ---- one-time LDS fill: 64 rows x 2KB, swizzled byte ^= (row&7)<<4 ----
  #pragma unroll
  for (int p = 0; p < 32; ++p) {
    int q = tid + p * 256;
    int flat = q * 16;
    int lrow = flat >> 11;
    int off = flat & 2047;
    int dst = flat ^ ((lrow & 7) << 4);
    const ushort_t* src;
    if (lrow < 16)      src = WhhH + (size_t)(c0 + lrow) * HDIM;
    else if (lrow < 32) src = WhhH + (size_t)(1024 + c0 + lrow - 16) * HDIM;
    else if (lrow < 48) src = WhhH + (size_t)(2048 + c0 + lrow - 32) * HDIM;
    else                src = WhhL + (size_t)(2048 + c0 + lrow - 48) * HDIM;
    *(sh8*)(lds + dst) = *(const sh8*)(src + (off >> 1));
  }
  __syncthreads();

  const float br = bias_hh[c], bz = bias_hh[1024 + c], bn = bias_hh[2048 + c];
  unsigned bar = 0;

  // own-column h carried exactly in fp32 registers across the whole sequence
  float hold[4];
  #pragma unroll
  for (int j = 0; j < 4; ++j) hold[j] = h0f[(m0 + rb + j) * HDIM + c];

  // prefetch gx r,z,n for t=0
  float gxr[4], gxz[4], gxn[4];
  #pragma unroll
  for (int j = 0; j < 4; ++j) {
    int b = m0 + rb + j;
    gxr[j] = __builtin_nontemporal_load(gx + (size_t)b * G3 + c);
    gxz[j] = __builtin_nontemporal_load(gx + (size_t)b * G3 + 1024 + c);
    gxn[j] = __builtin_nontemporal_load(gx + (size_t)b * G3 + 2048 + c);
  }

  for (int t = 0; t < SEQL; ++t) {
    const int par = t & 1;

    // ---- stage 1: h burst (agent atomics, single round trip), r,z GEMM ----
    unsigned* ha = hU + par * BH + (m0 + lr) * HDIM + lk;
    sh8 bufa[32];
    LOADU(bufa, ha)

    f32x4 accR = (f32x4){0,0,0,0}, accZ = (f32x4){0,0,0,0};
    #pragma unroll
    for (int i = 0; i < 32; ++i) {
      int byt = ((lr << 11) + ((i * 32 + lk) << 1)) ^ ((lr & 7) << 4);
      sh8 rW = *(const sh8*)(lds + byt);
      sh8 zW = *(const sh8*)(lds + 32768 + byt);
      accR = MFMA16(bufa[i], rW, accR);
      accZ = MFMA16(bufa[i], zW, accZ);
    }

    float zreg[4];
    #pragma unroll
    for (int j = 0; j < 4; ++j) {
      int b = m0 + rb + j;
      float pr = accR[j] + gxr[j] + br;
      float pz = accZ[j] + gxz[j] + bz;
      float r = 1.f / (1.f + __expf(-pr));
      zreg[j] = 1.f / (1.f + __expf(-pz));
      __hip_atomic_store(rhU + b * HDIM + c, (unsigned)f2bf(r * hold[j]),
                         __ATOMIC_RELAXED, __HIP_MEMORY_SCOPE_AGENT);
    }
    ++bar;
    gbar_nf(slots, g, tid, bar);

    // ---- stage 2: rh burst; gx[t+1] r,z prefetch; n GEMM (W hi+lo) ----
    unsigned* ra = rhU + (m0 + lr) * HDIM + lk;
    LOADU(bufa, ra)

    {
      int tn = (t + 1 < SEQL) ? t + 1 : t;
      const float* gxt1 = gx + (size_t)tn * (BATCH * G3);
      #pragma unroll
      for (int j = 0; j < 4; ++j) {
        int b = m0 + rb + j;
        gxr[j] = __builtin_nontemporal_load(gxt1 + (size_t)b * G3 + c);
        gxz[j] = __builtin_nontemporal_load(gxt1 + (size_t)b * G3 + 1024 + c);
      }
    }

    f32x4 accN = (f32x4){0,0,0,0};
    #pragma unroll
    for (int i = 0; i < 32; ++i) {
      int byt = ((lr << 11) + ((i * 32 + lk) << 1)) ^ ((lr & 7) << 4);
      sh8 nW = *(const sh8*)(lds + 65536 + byt);
      sh8 nLo = *(const sh8*)(lds + 98304 + byt);
      accN = MFMA16(bufa[i], nW, accN);
      accN = MFMA16(bufa[i], nLo, accN);
    }

    float gxnN[4];
    {
      int tn = (t + 1 < SEQL) ? t + 1 : t;
      const float* gxt1 = gx + (size_t)tn * (BATCH * G3);
      #pragma unroll
      for (int j = 0; j < 4; ++j) {
        int b = m0 + rb + j;
        gxnN[j] = __builtin_nontemporal_load(gxt1 + (size_t)b * G3 + 2048 + c);
      }
    }

    unsigned* hUn = hU + (par ^ 1) * BH;
    #pragma unroll
    for (int j = 0; j < 4; ++j) {
      int b = m0 + rb + j;
      float pn = accN[j] + gxn[j] + bn;
      float n = tanhf(pn);
      float z = zreg[j];
      float hnew = (1.f - z) * n + z * hold[j];
      hold[j] = hnew;
      Y[(size_t)t * BH + b * HDIM + c] = hnew;    // normal store (L2-fast ack)
      __hip_atomic_store(hUn + b * HDIM + c, (unsigned)f2bf(hnew),
                         __ATOMIC_RELAXED, __HIP_MEMORY_SCOPE_AGENT);
      if (t == SEQL - 1) Yh[b * HDIM + c] = hnew;
    }
    #pragma unroll
    for (int j = 0; j < 4; ++j) gxn[j] = gxnN[j];

    if (t < SEQL - 1) {
      ++bar;
      gbar_nf(slots, g, tid, bar);
    }
  }
}

// ---------------- launch ----------------
extern "C" void kernel_launch(void* const* d_in, const int* in_sizes, int n_in,
                              void* d_out, int out_size, void* d_ws, size_t ws_size,
                              hipStream_t stream) {
  const float* input = (const float*)d_in[0];
  const float* h0    = (const float*)d_in[1];
  const float* wih   = (const float*)d_in[2];
  const float* whh   = (const float*)d_in[3];
  const float* bih   = (const float*)d_in[4];
  const float* bhh   = (const float*)d_in[5];

  char* ws = (char*)d_ws;
  size_t o = 0;
  float* gx = (float*)(ws + o);         o += (size_t)AROWS * G3 * 4;
  ushort_t* WihH = (ushort_t*)(ws + o); o += (size_t)G3 * HDIM * 2;
  ushort_t* WihL = (ushort_t*)(ws + o); o += (size_t)G3 * HDIM * 2;
  ushort_t* WhhH = (ushort_t*)(ws + o); o += (size_t)G3 * HDIM * 2;
  ushort_t* WhhL = (ushort_t*)(ws + o); o += (size_t)G3 * HDIM * 2;
  unsigned* hU = (unsigned*)(ws + o);   o += 2 * (size_t)BH * 4;
  unsigned* rhU = (unsigned*)(ws + o);  o += (size_t)BH * 4;
  unsigned* slots = (unsigned*)(ws + o); o += 256;

  float* Y  = (float*)d_out;
  float* Yh = (float*)d_out + (size_t)YSZ;

  (void)hipFuncSetAttribute((const void*)gru_rec,
                            hipFuncAttributeMaxDynamicSharedMemorySize, 131072);

  (void)hipMemsetAsync(slots, 0, 256, stream);
  cvt_kernel<<<2048, 256, 0, stream>>>(wih, whh, h0, WihH, WihL, WhhH, WhhL, hU);
  gemm_gx<<<(AROWS / 128) * (G3 / 128), 256, 0, stream>>>(input, WihH, WihL, bih, gx);
  gru_rec<<<64, 256, 131072, stream>>>(gx, WhhH, WhhL, bhh, h0, hU, rhU, Y, Yh, slots);
}

// Round 14
// 9931.199 us; speedup vs baseline: 2.0319x; 2.0319x over previous
//
#include <hip/hip_runtime.h>

typedef unsigned short ushort_t;
typedef short sh8 __attribute__((ext_vector_type(8)));     // 8 bf16 (4 VGPR)
typedef float f32x4 __attribute__((ext_vector_type(4)));   // 4 fp32 acc

#define MFMA16(a,b,c) __builtin_amdgcn_mfma_f32_16x16x32_bf16((a),(b),(c),0,0,0)

#define SEQL   512
#define BATCH  64
#define HDIM   1024
#define G3     3072
#define AROWS  (SEQL*BATCH)          // 32768
#define YSZ    (SEQL*BATCH*HDIM)     // 33554432
#define BH     (BATCH*HDIM)          // 65536
#define NWG    64

__device__ __forceinline__ ushort_t f2bf(float x) {
  unsigned u = __float_as_uint(x);
  u += 0x7FFFu + ((u >> 16) & 1u);    // RNE
  return (ushort_t)(u >> 16);
}
__device__ __forceinline__ float bf2f(ushort_t h) {
  return __uint_as_float(((unsigned)h) << 16);
}

// ---------------- conversion / init ----------------
__global__ void cvt_kernel(const float* __restrict__ wih, const float* __restrict__ whh,
                           const float* __restrict__ h0,
                           ushort_t* __restrict__ WihH, ushort_t* __restrict__ WihL,
                           ushort_t* __restrict__ WhhH, ushort_t* __restrict__ WhhL,
                           ushort_t* __restrict__ hH) {
  const int NW = G3 * HDIM;
  int i0 = blockIdx.x * blockDim.x + threadIdx.x;
  int stride = gridDim.x * blockDim.x;
  for (int i = i0; i < NW; i += stride) {
    float x = wih[i]; ushort_t h = f2bf(x);
    WihH[i] = h; WihL[i] = f2bf(x - bf2f(h));
    float y = whh[i]; ushort_t g = f2bf(y);
    WhhH[i] = g; WhhL[i] = f2bf(y - bf2f(g));
  }
  for (int i = i0; i < BH; i += stride) {
    hH[i] = f2bf(h0[i]);
  }
}

// ---------------- phase 1: gx = input @ W_ih^T + b_ih (3-term bf16) ----------------
__global__ __launch_bounds__(256) void gemm_gx(
    const float* __restrict__ A,            // [32768][1024] fp32
    const ushort_t* __restrict__ BHp, const ushort_t* __restrict__ BLp, // [3072][1024]
    const float* __restrict__ bias,         // [3072]
    float* __restrict__ gx)                 // [32768][3072]
{
  int bid = blockIdx.x;
  int mt = bid / 24, nt = bid % 24;
  int w = threadIdx.x >> 6, l = threadIdx.x & 63;
  int lr = l & 15, lk = (l >> 4) * 8;

  f32x4 acc[2][8];
  #pragma unroll
  for (int mi = 0; mi < 2; ++mi)
    #pragma unroll
    for (int ni = 0; ni < 8; ++ni) acc[mi][ni] = (f32x4){0.f, 0.f, 0.f, 0.f};

  int arow0 = mt * 128 + w * 32 + lr;
  int brow0 = nt * 128 + lr;

  for (int k0 = 0; k0 < HDIM; k0 += 32) {
    int ka = k0 + lk;
    sh8 aH[2], aL[2];
    #pragma unroll
    for (int mi = 0; mi < 2; ++mi) {
      const float* ap = A + (size_t)(arow0 + mi * 16) * HDIM + ka;
      float4 x0 = *(const float4*)ap;
      float4 x1 = *(const float4*)(ap + 4);
      float xs[8] = {x0.x, x0.y, x0.z, x0.w, x1.x, x1.y, x1.z, x1.w};
      #pragma unroll
      for (int j = 0; j < 8; ++j) {
        ushort_t h = f2bf(xs[j]);
        aH[mi][j] = (short)h;
        aL[mi][j] = (short)f2bf(xs[j] - bf2f(h));
      }
    }
    #pragma unroll
    for (int ni = 0; ni < 8; ++ni) {
      const ushort_t* bh = BHp + (size_t)(brow0 + ni * 16) * HDIM + ka;
      const ushort_t* bl = BLp + (size_t)(brow0 + ni * 16) * HDIM + ka;
      sh8 bHf = *(const sh8*)bh;
      sh8 bLf = *(const sh8*)bl;
      #pragma unroll
      for (int mi = 0; mi < 2; ++mi) {
        acc[mi][ni] = MFMA16(aH[mi], bHf, acc[mi][ni]);
        acc[mi][ni] = MFMA16(aH[mi], bLf, acc[mi][ni]);
        acc[mi][ni] = MFMA16(aL[mi], bHf, acc[mi][ni]);
      }
    }
  }
  int rb = (l >> 4) * 4;
  #pragma unroll
  for (int mi = 0; mi < 2; ++mi)
    #pragma unroll
    for (int ni = 0; ni < 8; ++ni) {
      int col = nt * 128 + ni * 16 + lr;
      float b = bias[col];
      #pragma unroll
      for (int j = 0; j < 4; ++j) {
        int row = mt * 128 + w * 32 + mi * 16 + rb + j;
        __builtin_nontemporal_store(acc[mi][ni][j] + b, &gx[(size_t)row * G3 + col]);
      }
    }
}

// ---------------- flat single-hop device barrier, busy-spin + dense slots ----------------
// Dense slots (64 uints = 4 cachelines): poll gather touches 4 hot lines, not 64.
// Busy spin with FMA pacing (NO s_sleep): keeps one SIMD per CU issuing at all times
// so the chip cannot fall into an idle power state while waiting (DVFS probe).
__device__ __forceinline__ void gbar_flat(unsigned* slots, int g, int tid, unsigned e) {
  __syncthreads();
  if (tid < 64) {
    if (tid == 0)
      __hip_atomic_store(slots + g, e, __ATOMIC_RELEASE, __HIP_MEMORY_SCOPE_AGENT);
    float x = (float)(e & 255u);
    while (__hip_atomic_load(slots + tid, __ATOMIC_RELAXED, __HIP_MEMORY_SCOPE_AGENT) < e) {
      #pragma unroll
      for (int it = 0; it < 8; ++it) x = __builtin_fmaf(x, 1.0000001f, 1e-7f);
      asm volatile("" : "+v"(x));   // keep the chain live; paces poll rate
    }
    (void)__hip_atomic_load(slots + tid, __ATOMIC_ACQUIRE, __HIP_MEMORY_SCOPE_AGENT);
  }
  __syncthreads();
}

// ---------------- phase 2: persistent recurrence ----------------
// 64 WGs x 256 threads. WG g owns hidden cols [16g,16g+16). Wave w owns rows [16w,16w+16).
// W_hh slices in LDS (128KB): rH@0, zH@32K, nH@64K, nL@96K, XOR-swizzled.
// Exchange (hH, rhH) via normal stores (L2; release wbL2 -> L3). Y/gx nontemporal.
__global__ __launch_bounds__(256, 1) void gru_rec(
    const float* __restrict__ gx,                 // [512][64][3072]
    const ushort_t* __restrict__ WhhH, const ushort_t* __restrict__ WhhL, // [3072][1024]
    const float* __restrict__ bias_hh,            // [3072]
    const float* __restrict__ h0f,                // [64][1024] fp32
    ushort_t* __restrict__ hH,                    // [2][64][1024]
    ushort_t* __restrict__ rhH,                   // [64][1024]
    float* __restrict__ Y, float* __restrict__ Yh,
    unsigned* __restrict__ slots)
{
  extern __shared__ char lds[];
  const int g = blockIdx.x;
  const int tid = threadIdx.x;
  const int w = tid >> 6, l = tid & 63;
  const int lr = l & 15, lk = (l >> 4) * 8, rb = (l >> 4) * 4;
  const int c0 = g * 16, m0 = w * 16;
  const int c = c0 + lr;

  // ---- one-time LDS fill: 64 rows x 2KB, swizzled byte ^= (row&7)<<4 ----
  #pragma unroll
  for (int p = 0; p < 32; ++p) {
    int q = tid + p * 256;
    int flat = q * 16;
    int lrow = flat >> 11;
    int off = flat & 2047;
    int dst = flat ^ ((lrow & 7) << 4);
    const ushort_t* src;
    if (lrow < 16)      src = WhhH + (size_t)(c0 + lrow) * HDIM;
    else if (lrow < 32) src = WhhH + (size_t)(1024 + c0 + lrow - 16) * HDIM;
    else if (lrow < 48) src = WhhH + (size_t)(2048 + c0 + lrow - 32) * HDIM;
    else                src = WhhL + (size_t)(2048 + c0 + lrow - 48) * HDIM;
    *(sh8*)(lds + dst) = *(const sh8*)(src + (off >> 1));
  }
  __syncthreads();

  const float br = bias_hh[c], bz = bias_hh[1024 + c], bn = bias_hh[2048 + c];
  unsigned bar = 0;

  // own-column h carried exactly in fp32 registers across the whole sequence
  float hold[4];
  #pragma unroll
  for (int j = 0; j < 4; ++j) hold[j] = h0f[(m0 + rb + j) * HDIM + c];

  // prefetch gx r,z,n for t=0
  float gxr[4], gxz[4], gxn[4];
  #pragma unroll
  for (int j = 0; j < 4; ++j) {
    int b = m0 + rb + j;
    gxr[j] = __builtin_nontemporal_load(gx + (size_t)b * G3 + c);
    gxz[j] = __builtin_nontemporal_load(gx + (size_t)b * G3 + 1024 + c);
    gxn[j] = __builtin_nontemporal_load(gx + (size_t)b * G3 + 2048 + c);
  }

  for (int t = 0; t < SEQL; ++t) {
    const int par = t & 1;

    // ---- stage 1: full-burst h load, then r,z GEMM (h hi-only) ----
    const ushort_t* ha = hH + par * BH + (size_t)(m0 + lr) * HDIM + lk;
    sh8 bufa[32];
    #pragma unroll
    for (int i = 0; i < 32; ++i) bufa[i] = *(const sh8*)(ha + i * 32);

    f32x4 accR = (f32x4){0,0,0,0}, accZ = (f32x4){0,0,0,0};
    #pragma unroll
    for (int i = 0; i < 32; ++i) {
      int byt = ((lr << 11) + ((i * 32 + lk) << 1)) ^ ((lr & 7) << 4);
      sh8 rW = *(const sh8*)(lds + byt);
      sh8 zW = *(const sh8*)(lds + 32768 + byt);
      accR = MFMA16(bufa[i], rW, accR);
      accZ = MFMA16(bufa[i], zW, accZ);
    }

    float zreg[4];
    #pragma unroll
    for (int j = 0; j < 4; ++j) {
      int b = m0 + rb + j;
      float pr = accR[j] + gxr[j] + br;
      float pz = accZ[j] + gxz[j] + bz;
      float r = 1.f / (1.f + __expf(-pr));
      zreg[j] = 1.f / (1.f + __expf(-pz));
      rhH[b * HDIM + c] = f2bf(r * hold[j]);      // normal store (stays cached)
    }
    ++bar;
    gbar_flat(slots, g, tid, bar);

    // ---- stage 2: full-burst rh load; prefetch gx[t+1]; n GEMM (rh hi-only) ----
    const ushort_t* ra = rhH + (size_t)(m0 + lr) * HDIM + lk;
    #pragma unroll
    for (int i = 0; i < 32; ++i) bufa[i] = *(const sh8*)(ra + i * 32);

    {
      int tn = (t + 1 < SEQL) ? t + 1 : t;
      const float* gxn2 = gx + (size_t)tn * (BATCH * G3);
      #pragma unroll
      for (int j = 0; j < 4; ++j) {
        int b = m0 + rb + j;
        gxr[j] = __builtin_nontemporal_load(gxn2 + (size_t)b * G3 + c);
        gxz[j] = __builtin_nontemporal_load(gxn2 + (size_t)b * G3 + 1024 + c);
      }
    }

    f32x4 accN = (f32x4){0,0,0,0};
    #pragma unroll
    for (int i = 0; i < 32; ++i) {
      int byt = ((lr << 11) + ((i * 32 + lk) << 1)) ^ ((lr & 7) << 4);
      sh8 nW = *(const sh8*)(lds + 65536 + byt);
      sh8 nLo = *(const sh8*)(lds + 98304 + byt);
      accN = MFMA16(bufa[i], nW, accN);
      accN = MFMA16(bufa[i], nLo, accN);
    }

    ushort_t* hHn = hH + (par ^ 1) * BH;
    float gxnN[4];
    {
      int tn = (t + 1 < SEQL) ? t + 1 : t;
      const float* gxn2 = gx + (size_t)tn * (BATCH * G3);
      #pragma unroll
      for (int j = 0; j < 4; ++j) {
        int b = m0 + rb + j;
        gxnN[j] = __builtin_nontemporal_load(gxn2 + (size_t)b * G3 + 2048 + c);
      }
    }
    #pragma unroll
    for (int j = 0; j < 4; ++j) {
      int b = m0 + rb + j;
      float pn = accN[j] + gxn[j] + bn;
      float n = tanhf(pn);
      float z = zreg[j];
      float hnew = (1.f - z) * n + z * hold[j];
      hold[j] = hnew;
      __builtin_nontemporal_store(hnew, &Y[(size_t)t * BH + b * HDIM + c]);
      hHn[b * HDIM + c] = f2bf(hnew);             // normal store (stays cached)
      if (t == SEQL - 1) __builtin_nontemporal_store(hnew, &Yh[b * HDIM + c]);
    }
    #pragma unroll
    for (int j = 0; j < 4; ++j) gxn[j] = gxnN[j];

    if (t < SEQL - 1) {
      ++bar;
      gbar_flat(slots, g, tid, bar);
    }
  }
}

// ---------------- launch ----------------
extern "C" void kernel_launch(void* const* d_in, const int* in_sizes, int n_in,
                              void* d_out, int out_size, void* d_ws, size_t ws_size,
                              hipStream_t stream) {
  const float* input = (const float*)d_in[0];
  const float* h0    = (const float*)d_in[1];
  const float* wih   = (const float*)d_in[2];
  const float* whh   = (const float*)d_in[3];
  const float* bih   = (const float*)d_in[4];
  const float* bhh   = (const float*)d_in[5];

  char* ws = (char*)d_ws;
  size_t o = 0;
  float* gx = (float*)(ws + o);         o += (size_t)AROWS * G3 * 4;
  ushort_t* WihH = (ushort_t*)(ws + o); o += (size_t)G3 * HDIM * 2;
  ushort_t* WihL = (ushort_t*)(ws + o); o += (size_t)G3 * HDIM * 2;
  ushort_t* WhhH = (ushort_t*)(ws + o); o += (size_t)G3 * HDIM * 2;
  ushort_t* WhhL = (ushort_t*)(ws + o); o += (size_t)G3 * HDIM * 2;
  ushort_t* hH = (ushort_t*)(ws + o);   o += 2 * (size_t)BH * 2;
  ushort_t* rhH = (ushort_t*)(ws + o);  o += (size_t)BH * 2;
  unsigned* slots = (unsigned*)(ws + o); o += 256;

  float* Y  = (float*)d_out;
  float* Yh = (float*)d_out + (size_t)YSZ;

  (void)hipFuncSetAttribute((const void*)gru_rec,
                            hipFuncAttributeMaxDynamicSharedMemorySize, 131072);

  (void)hipMemsetAsync(slots, 0, 256, stream);
  cvt_kernel<<<2048, 256, 0, stream>>>(wih, whh, h0, WihH, WihL, WhhH, WhhL, hH);
  gemm_gx<<<(AROWS / 128) * (G3 / 128), 256, 0, stream>>>(input, WihH, WihL, bih, gx);
  gru_rec<<<64, 256, 131072, stream>>>(gx, WhhH, WhhL, bhh, h0, hH, rhH, Y, Yh, slots);
}

// Round 15
// 8682.401 us; speedup vs baseline: 2.3241x; 1.1438x over previous
//
#include <hip/hip_runtime.h>

typedef unsigned short ushort_t;
typedef short sh8 __attribute__((ext_vector_type(8)));     // 8 bf16 (4 VGPR)
typedef float f32x4 __attribute__((ext_vector_type(4)));   // 4 fp32 acc

#define MFMA16(a,b,c) __builtin_amdgcn_mfma_f32_16x16x32_bf16((a),(b),(c),0,0,0)

#define SEQL   512
#define BATCH  64
#define HDIM   1024
#define G3     3072
#define AROWS  (SEQL*BATCH)          // 32768
#define YSZ    (SEQL*BATCH*HDIM)     // 33554432
#define BH     (BATCH*HDIM)          // 65536
#define NWG    64                    // rec WGs
#define NGEMM  192                   // producer WGs
#define NTILE  768                   // (32768/128)*(3072/128)... = 256*24/8? -> 256 mt? no: 256 mt-blocks x 24 nt = 6144? see below

// NOTE: tiles are 128x128: mt in [0,256), nt in [0,24) -> 6144 tiles is wrong; rows 32768/128=256, cols 3072/128=24 -> 6144 tiles
// 6144 tiles / 192 WGs = 32 tiles per WG.
#define TILES_TOTAL (256*24)
#define TILES_PER_WG (TILES_TOTAL/NGEMM)   // 32

__device__ __forceinline__ ushort_t f2bf(float x) {
  unsigned u = __float_as_uint(x);
  u += 0x7FFFu + ((u >> 16) & 1u);    // RNE
  return (ushort_t)(u >> 16);
}
__device__ __forceinline__ float bf2f(ushort_t h) {
  return __uint_as_float(((unsigned)h) << 16);
}

// ---------------- conversion / init ----------------
__global__ void cvt_kernel(const float* __restrict__ wih, const float* __restrict__ whh,
                           const float* __restrict__ h0,
                           ushort_t* __restrict__ WihH, ushort_t* __restrict__ WihL,
                           ushort_t* __restrict__ WhhH, ushort_t* __restrict__ WhhL,
                           ushort_t* __restrict__ hH) {
  const int NW = G3 * HDIM;
  int i0 = blockIdx.x * blockDim.x + threadIdx.x;
  int stride = gridDim.x * blockDim.x;
  for (int i = i0; i < NW; i += stride) {
    float x = wih[i]; ushort_t h = f2bf(x);
    WihH[i] = h; WihL[i] = f2bf(x - bf2f(h));
    float y = whh[i]; ushort_t g = f2bf(y);
    WhhH[i] = g; WhhL[i] = f2bf(y - bf2f(g));
  }
  for (int i = i0; i < BH; i += stride) {
    hH[i] = f2bf(h0[i]);
  }
}

// ---------------- flat single-hop device barrier (R11 verbatim) ----------------
__device__ __forceinline__ void gbar_flat(unsigned* slots, int g, int tid, unsigned e) {
  __syncthreads();
  if (tid < 64) {
    if (tid == 0)
      __hip_atomic_store(slots + g * 32, e, __ATOMIC_RELEASE, __HIP_MEMORY_SCOPE_AGENT);
    unsigned* sp = slots + tid * 32;
    while (__hip_atomic_load(sp, __ATOMIC_RELAXED, __HIP_MEMORY_SCOPE_AGENT) < e)
      __builtin_amdgcn_s_sleep(1);
    (void)__hip_atomic_load(sp, __ATOMIC_ACQUIRE, __HIP_MEMORY_SCOPE_AGENT);
  }
  __syncthreads();
}

// ---------------- fused persistent kernel ----------------
// 256 WGs x 256 threads, 128KB dynamic LDS each => exactly 1 WG/CU => all co-resident.
// WGs 0..63: GRU recurrence (R11 verbatim + gx progress gating).
// WGs 64..255: gx GEMM producers, 32 tiles each in mt-ascending order; release prog[mt].
__global__ __launch_bounds__(256, 1) void mega(
    const float* __restrict__ A,                  // input [32768][1024] fp32
    const ushort_t* __restrict__ WihH, const ushort_t* __restrict__ WihL,
    const float* __restrict__ bih,
    float* __restrict__ gx,                       // [512][64][3072]
    const ushort_t* __restrict__ WhhH, const ushort_t* __restrict__ WhhL,
    const float* __restrict__ bhh,
    const float* __restrict__ h0f,
    ushort_t* __restrict__ hH,                    // [2][64][1024]
    ushort_t* __restrict__ rhH,                   // [64][1024]
    float* __restrict__ Y, float* __restrict__ Yh,
    unsigned* __restrict__ slots,
    unsigned* __restrict__ prog)                  // [256] tiles-done per mt-block
{
  extern __shared__ char lds[];
  const int g = blockIdx.x;
  const int tid = threadIdx.x;
  const int w = tid >> 6, l = tid & 63;
  const int lr = l & 15, lk = (l >> 4) * 8, rb = (l >> 4) * 4;

  if (g >= NWG) {
    // ================= producer path =================
    const int base = g - NWG;
    for (int kk = 0; kk < TILES_PER_WG; ++kk) {
      int tile = base + NGEMM * kk;              // mt-ascending across rounds
      int mt = tile / 24, nt = tile % 24;

      f32x4 acc[2][8];
      #pragma unroll
      for (int mi = 0; mi < 2; ++mi)
        #pragma unroll
        for (int ni = 0; ni < 8; ++ni) acc[mi][ni] = (f32x4){0.f, 0.f, 0.f, 0.f};

      int arow0 = mt * 128 + w * 32 + lr;
      int brow0 = nt * 128 + lr;

      for (int k0 = 0; k0 < HDIM; k0 += 32) {
        int ka = k0 + lk;
        sh8 aH[2], aL[2];
        #pragma unroll
        for (int mi = 0; mi < 2; ++mi) {
          const float* ap = A + (size_t)(arow0 + mi * 16) * HDIM + ka;
          float4 x0 = *(const float4*)ap;
          float4 x1 = *(const float4*)(ap + 4);
          float xs[8] = {x0.x, x0.y, x0.z, x0.w, x1.x, x1.y, x1.z, x1.w};
          #pragma unroll
          for (int j = 0; j < 8; ++j) {
            ushort_t h = f2bf(xs[j]);
            aH[mi][j] = (short)h;
            aL[mi][j] = (short)f2bf(xs[j] - bf2f(h));
          }
        }
        #pragma unroll
        for (int ni = 0; ni < 8; ++ni) {
          const ushort_t* bh = WihH + (size_t)(brow0 + ni * 16) * HDIM + ka;
          const ushort_t* bl = WihL + (size_t)(brow0 + ni * 16) * HDIM + ka;
          sh8 bHf = *(const sh8*)bh;
          sh8 bLf = *(const sh8*)bl;
          #pragma unroll
          for (int mi = 0; mi < 2; ++mi) {
            acc[mi][ni] = MFMA16(aH[mi], bHf, acc[mi][ni]);
            acc[mi][ni] = MFMA16(aH[mi], bLf, acc[mi][ni]);
            acc[mi][ni] = MFMA16(aL[mi], bHf, acc[mi][ni]);
          }
        }
      }
      int rbq = (l >> 4) * 4;
      #pragma unroll
      for (int mi = 0; mi < 2; ++mi)
        #pragma unroll
        for (int ni = 0; ni < 8; ++ni) {
          int col = nt * 128 + ni * 16 + lr;
          float b = bih[col];
          #pragma unroll
          for (int j = 0; j < 4; ++j) {
            int row = mt * 128 + w * 32 + mi * 16 + rbq + j;
            __builtin_nontemporal_store(acc[mi][ni][j] + b, &gx[(size_t)row * G3 + col]);
          }
        }
      __syncthreads();   // all waves' stores issued before the release below
      if (tid == 0)
        __hip_atomic_fetch_add(prog + mt, 1u, __ATOMIC_RELEASE, __HIP_MEMORY_SCOPE_AGENT);
    }
    return;
  }

  // ================= recurrence path (R11 verbatim + progress gating) =================
  const int c0 = g * 16, m0 = w * 16;
  const int c = c0 + lr;

  // ---- one-time LDS fill: 64 rows x 2KB, swizzled byte ^= (row&7)<<4 ----
  #pragma unroll
  for (int p = 0; p < 32; ++p) {
    int q = tid + p * 256;
    int flat = q * 16;
    int lrow = flat >> 11;
    int off = flat & 2047;
    int dst = flat ^ ((lrow & 7) << 4);
    const ushort_t* src;
    if (lrow < 16)      src = WhhH + (size_t)(c0 + lrow) * HDIM;
    else if (lrow < 32) src = WhhH + (size_t)(1024 + c0 + lrow - 16) * HDIM;
    else if (lrow < 48) src = WhhH + (size_t)(2048 + c0 + lrow - 32) * HDIM;
    else                src = WhhL + (size_t)(2048 + c0 + lrow - 48) * HDIM;
    *(sh8*)(lds + dst) = *(const sh8*)(src + (off >> 1));
  }
  __syncthreads();

  const float br = bhh[c], bz = bhh[1024 + c], bn = bhh[2048 + c];
  unsigned bar = 0;
  int pready = 0;

  float hold[4];
  #pragma unroll
  for (int j = 0; j < 4; ++j) hold[j] = h0f[(m0 + rb + j) * HDIM + c];

  // wait for gx block 0 (t=0,1), then prefetch gx r,z,n for t=0
  {
    while (__hip_atomic_load(prog, __ATOMIC_RELAXED, __HIP_MEMORY_SCOPE_AGENT) < 24u)
      __builtin_amdgcn_s_sleep(1);
    (void)__hip_atomic_load(prog, __ATOMIC_ACQUIRE, __HIP_MEMORY_SCOPE_AGENT);
    pready = 1;
  }
  float gxr[4], gxz[4], gxn[4];
  #pragma unroll
  for (int j = 0; j < 4; ++j) {
    int b = m0 + rb + j;
    gxr[j] = __builtin_nontemporal_load(gx + (size_t)b * G3 + c);
    gxz[j] = __builtin_nontemporal_load(gx + (size_t)b * G3 + 1024 + c);
    gxn[j] = __builtin_nontemporal_load(gx + (size_t)b * G3 + 2048 + c);
  }

  for (int t = 0; t < SEQL; ++t) {
    const int par = t & 1;

    // ---- stage 1: full-burst h load, then r,z GEMM (h hi-only) ----
    const ushort_t* ha = hH + par * BH + (size_t)(m0 + lr) * HDIM + lk;
    sh8 bufa[32];
    #pragma unroll
    for (int i = 0; i < 32; ++i) bufa[i] = *(const sh8*)(ha + i * 32);

    f32x4 accR = (f32x4){0,0,0,0}, accZ = (f32x4){0,0,0,0};
    #pragma unroll
    for (int i = 0; i < 32; ++i) {
      int byt = ((lr << 11) + ((i * 32 + lk) << 1)) ^ ((lr & 7) << 4);
      sh8 rW = *(const sh8*)(lds + byt);
      sh8 zW = *(const sh8*)(lds + 32768 + byt);
      accR = MFMA16(bufa[i], rW, accR);
      accZ = MFMA16(bufa[i], zW, accZ);
    }

    float zreg[4];
    #pragma unroll
    for (int j = 0; j < 4; ++j) {
      int b = m0 + rb + j;
      float pr = accR[j] + gxr[j] + br;
      float pz = accZ[j] + gxz[j] + bz;
      float r = 1.f / (1.f + __expf(-pr));
      zreg[j] = 1.f / (1.f + __expf(-pz));
      rhH[b * HDIM + c] = f2bf(r * hold[j]);      // normal store (stays cached)
    }
    ++bar;
    gbar_flat(slots, g, tid, bar);

    // ---- stage 2: full-burst rh load; gated gx[t+1] prefetch; n GEMM ----
    const ushort_t* ra = rhH + (size_t)(m0 + lr) * HDIM + lk;
    #pragma unroll
    for (int i = 0; i < 32; ++i) bufa[i] = *(const sh8*)(ra + i * 32);

    int tn = (t + 1 < SEQL) ? t + 1 : t;
    {
      int blk = tn >> 1;
      if (blk >= pready) {
        while (__hip_atomic_load(prog + blk, __ATOMIC_RELAXED, __HIP_MEMORY_SCOPE_AGENT) < 24u)
          __builtin_amdgcn_s_sleep(1);
        (void)__hip_atomic_load(prog + blk, __ATOMIC_ACQUIRE, __HIP_MEMORY_SCOPE_AGENT);
        pready = blk + 1;
      }
      const float* gxn2 = gx + (size_t)tn * (BATCH * G3);
      #pragma unroll
      for (int j = 0; j < 4; ++j) {
        int b = m0 + rb + j;
        gxr[j] = __builtin_nontemporal_load(gxn2 + (size_t)b * G3 + c);
        gxz[j] = __builtin_nontemporal_load(gxn2 + (size_t)b * G3 + 1024 + c);
      }
    }

    f32x4 accN = (f32x4){0,0,0,0};
    #pragma unroll
    for (int i = 0; i < 32; ++i) {
      int byt = ((lr << 11) + ((i * 32 + lk) << 1)) ^ ((lr & 7) << 4);
      sh8 nW = *(const sh8*)(lds + 65536 + byt);
      sh8 nLo = *(const sh8*)(lds + 98304 + byt);
      accN = MFMA16(bufa[i], nW, accN);
      accN = MFMA16(bufa[i], nLo, accN);
    }

    ushort_t* hHn = hH + (par ^ 1) * BH;
    float gxnN[4];
    {
      const float* gxn2 = gx + (size_t)tn * (BATCH * G3);
      #pragma unroll
      for (int j = 0; j < 4; ++j) {
        int b = m0 + rb + j;
        gxnN[j] = __builtin_nontemporal_load(gxn2 + (size_t)b * G3 + 2048 + c);
      }
    }
    #pragma unroll
    for (int j = 0; j < 4; ++j) {
      int b = m0 + rb + j;
      float pn = accN[j] + gxn[j] + bn;
      float n = tanhf(pn);
      float z = zreg[j];
      float hnew = (1.f - z) * n + z * hold[j];
      hold[j] = hnew;
      __builtin_nontemporal_store(hnew, &Y[(size_t)t * BH + b * HDIM + c]);
      hHn[b * HDIM + c] = f2bf(hnew);             // normal store (stays cached)
      if (t == SEQL - 1) __builtin_nontemporal_store(hnew, &Yh[b * HDIM + c]);
    }
    #pragma unroll
    for (int j = 0; j < 4; ++j) gxn[j] = gxnN[j];

    if (t < SEQL - 1) {
      ++bar;
      gbar_flat(slots, g, tid, bar);
    }
  }
}

// ---------------- launch ----------------
extern "C" void kernel_launch(void* const* d_in, const int* in_sizes, int n_in,
                              void* d_out, int out_size, void* d_ws, size_t ws_size,
                              hipStream_t stream) {
  const float* input = (const float*)d_in[0];
  const float* h0    = (const float*)d_in[1];
  const float* wih   = (const float*)d_in[2];
  const float* whh   = (const float*)d_in[3];
  const float* bih   = (const float*)d_in[4];
  const float* bhh   = (const float*)d_in[5];

  char* ws = (char*)d_ws;
  size_t o = 0;
  float* gx = (float*)(ws + o);         o += (size_t)AROWS * G3 * 4;
  ushort_t* WihH = (ushort_t*)(ws + o); o += (size_t)G3 * HDIM * 2;
  ushort_t* WihL = (ushort_t*)(ws + o); o += (size_t)G3 * HDIM * 2;
  ushort_t* WhhH = (ushort_t*)(ws + o); o += (size_t)G3 * HDIM * 2;
  ushort_t* WhhL = (ushort_t*)(ws + o); o += (size_t)G3 * HDIM * 2;
  ushort_t* hH = (ushort_t*)(ws + o);   o += 2 * (size_t)BH * 2;
  ushort_t* rhH = (ushort_t*)(ws + o);  o += (size_t)BH * 2;
  unsigned* slots = (unsigned*)(ws + o); o += (size_t)NWG * 128;
  unsigned* prog = (unsigned*)(ws + o);  o += 256 * 4;

  float* Y  = (float*)d_out;
  float* Yh = (float*)d_out + (size_t)YSZ;

  (void)hipFuncSetAttribute((const void*)mega,
                            hipFuncAttributeMaxDynamicSharedMemorySize, 131072);

  (void)hipMemsetAsync(slots, 0, (size_t)NWG * 128 + 256 * 4, stream);
  cvt_kernel<<<2048, 256, 0, stream>>>(wih, whh, h0, WihH, WihL, WhhH, WhhL, hH);
  mega<<<NWG + NGEMM, 256, 131072, stream>>>(input, WihH, WihL, bih, gx,
                                             WhhH, WhhL, bhh, h0, hH, rhH,
                                             Y, Yh, slots, prog);
}